// Round 6
// baseline (165.865 us; speedup 1.0000x reference)
//
#include <hip/hip_runtime.h>
#include <hip/hip_bf16.h>
#include <math.h>

#define B_       512
#define SEQ_     25
#define C_       512
#define W_       5
#define BS_      2560          // B_*W_ rows per input
#define N_       5120          // 2*BS_
#define NT_      40            // N_/128 tile rows
#define NTILES_  (NT_ * (NT_ + 1) / 2)   // 820 upper-triangle tiles
#define CB4_     256           // bytes per zn row (512 fp4 nibbles)
#define TEMP_INV 10.0f
#define EPS_     1e-8f

typedef __attribute__((ext_vector_type(4))) int   int4v;
typedef __attribute__((ext_vector_type(8))) int   int8v;
typedef __attribute__((ext_vector_type(4))) float floatx4;

#define GAS(p) ((__attribute__((address_space(1))) void*)(void*)(p))
#define LAS(p) ((__attribute__((address_space(3))) void*)(p))

// e2m1 quantize of x (pre-scaled by 32): codes 0..7 = {0,.5,1,1.5,2,3,4,6}
static __device__ __forceinline__ uint fp4q(float x) {
    float m = fabsf(x);
    uint c;
    if      (m < 0.25f) c = 0;
    else if (m < 0.75f) c = 1;
    else if (m < 1.25f) c = 2;
    else if (m < 1.75f) c = 3;
    else if (m < 2.5f)  c = 4;
    else if (m < 3.5f)  c = 5;
    else if (m < 5.0f)  c = 6;
    else                c = 7;
    return c | (x < 0.f ? 8u : 0u);
}

// ---- kernel 1: pool (5-wide bins) + L2 normalize + fp4(e2m1) pack -----------
// One wave per output row; lane owns 8 contiguous channels -> one uint of
// 8 nibbles. Block scale 2^-5 folded here (x = v*inv*32), E8M0 0x7A in MFMA.
__global__ __launch_bounds__(256) void pool_norm_kernel(const float* __restrict__ zi,
                                                        const float* __restrict__ zj,
                                                        uint* __restrict__ zn4,
                                                        float* __restrict__ S,
                                                        uint* __restrict__ done) {
    int row = blockIdx.x * 4 + (threadIdx.x >> 6);
    int lane = threadIdx.x & 63;
    const float* src = (row < BS_) ? zi : zj;
    int rr = (row < BS_) ? row : row - BS_;
    int b = rr / W_;
    int w = rr - b * W_;
    const float4* base4 = (const float4*)(src + ((size_t)b * SEQ_ + (size_t)w * W_) * C_);
    float4 v0 = {0, 0, 0, 0}, v1 = {0, 0, 0, 0};
#pragma unroll
    for (int t = 0; t < W_; ++t) {
        float4 a = base4[t * 128 + lane * 2];
        float4 c = base4[t * 128 + lane * 2 + 1];
        v0.x += a.x; v0.y += a.y; v0.z += a.z; v0.w += a.w;
        v1.x += c.x; v1.y += c.y; v1.z += c.z; v1.w += c.w;
    }
    float ss = v0.x * v0.x + v0.y * v0.y + v0.z * v0.z + v0.w * v0.w
             + v1.x * v1.x + v1.y * v1.y + v1.z * v1.z + v1.w * v1.w;
#pragma unroll
    for (int m = 32; m >= 1; m >>= 1) ss += __shfl_xor(ss, m, 64);
    // 1/5 pooling scale folds into 1/norm (cosine is scale-invariant)
    float inv32 = 32.0f / fmaxf(sqrtf(ss), EPS_);
    uint p = fp4q(v0.x * inv32);
    p |= fp4q(v0.y * inv32) << 4;
    p |= fp4q(v0.z * inv32) << 8;
    p |= fp4q(v0.w * inv32) << 12;
    p |= fp4q(v1.x * inv32) << 16;
    p |= fp4q(v1.y * inv32) << 20;
    p |= fp4q(v1.z * inv32) << 24;
    p |= fp4q(v1.w * inv32) << 28;
    zn4[(size_t)row * 64 + lane] = p;
    if (lane == 0) S[row] = 0.f;                    // replaces memset launch
    if (row == 0 && lane == 0) done[0] = 0u;        // last-block counter init
}

// ---- kernel 2: upper-tri 128x128 tiles, MX-fp4, single-barrier K, fused loss
// Whole K fits in LDS at fp4 (2 x 4 x 8KB = 64KB): issue ALL global_load_lds,
// ONE barrier, then 64 MFMA with no further syncs — L2 latency paid once.
// Last block (device-scope counter) computes loss = sum(log S - pos)/N.
__global__ __launch_bounds__(256) void simexp_mfma(const unsigned char* __restrict__ zn,
                                                   float* __restrict__ S,
                                                   float* __restrict__ pos,
                                                   uint* __restrict__ done,
                                                   float* __restrict__ out) {
    __shared__ __align__(16) unsigned char As[4][128 * 64];
    __shared__ __align__(16) unsigned char Bs[4][128 * 64];
    // decode upper-triangle tile index (scalar, uniform)
    int t = blockIdx.x, rt = 0, rem = NT_;
    while (t >= rem) { t -= rem; rem--; rt++; }
    int ct = rt + t;

    int tid = threadIdx.x;
    int wid = tid >> 6, lane = tid & 63;
    int lrow = lane >> 2, lk = lane & 3;        // staging: 16 rows x 4 chunks of 16B
    int lx = lane & 15, quad = lane >> 4;       // mfma fragment indexing
    int wrow = (wid >> 1) * 64, wcol = (wid & 1) * 64;

    // stage the ENTIRE K range: 4 buffers x (2 row-groups x A/B) per wave
#pragma unroll
    for (int k = 0; k < 4; ++k) {
#pragma unroll
        for (int c = 0; c < 2; ++c) {
            int r = wid * 32 + c * 16 + lrow;
            int goff = (lk ^ (lrow & 3)) * 16 + k * 64;
            __builtin_amdgcn_global_load_lds(
                GAS(zn + (size_t)(rt * 128 + r) * CB4_ + goff),
                LAS(As[k] + (wid * 32 + c * 16) * 64), 16, 0, 0);
            __builtin_amdgcn_global_load_lds(
                GAS(zn + (size_t)(ct * 128 + r) * CB4_ + goff),
                LAS(Bs[k] + (wid * 32 + c * 16) * 64), 16, 0, 0);
        }
    }
    __syncthreads();                            // the ONLY barrier

    union frag { int8v v8; int4v v4[2]; };
    floatx4 acc[4][4] = {};
#pragma unroll
    for (int k = 0; k < 4; ++k) {
        frag af[4], bf[4];
#pragma unroll
        for (int tt = 0; tt < 4; ++tt) {
            int m = wrow + tt * 16 + lx;
            af[tt].v4[0] = *(const int4v*)&As[k][m * 64 + ((quad ^ (m & 3)) * 16)];
            af[tt].v4[1] = (int4v)(0);
            int n = wcol + tt * 16 + lx;
            bf[tt].v4[0] = *(const int4v*)&Bs[k][n * 64 + ((quad ^ (n & 3)) * 16)];
            bf[tt].v4[1] = (int4v)(0);
        }
#pragma unroll
        for (int i = 0; i < 4; ++i)
#pragma unroll
            for (int j = 0; j < 4; ++j)
                acc[i][j] = __builtin_amdgcn_mfma_scale_f32_16x16x128_f8f6f4(
                    af[i].v8, bf[j].v8, acc[i][j],
                    4, 4,                    // cbsz=fp4(e2m1), blgp=fp4(e2m1)
                    0, 0x7A7A7A7A,           // scale A: E8M0 2^-5
                    0, 0x7A7A7A7A);          // scale B: E8M0 2^-5
    }

    // epilogue: D layout col=lane&15, row=quad*4+reg (shape-determined)
    int colb = ct * 128 + wcol + lx;
    if (rt == ct) {
        // diagonal tile: mask diagonal, row sums only (pos never here)
#pragma unroll
        for (int i = 0; i < 4; ++i) {
#pragma unroll
            for (int r = 0; r < 4; ++r) {
                int m = rt * 128 + wrow + i * 16 + quad * 4 + r;
                float s = 0.f;
#pragma unroll
                for (int j = 0; j < 4; ++j) {
                    int cg = colb + j * 16;
                    float e = __expf(acc[i][j][r] * TEMP_INV);
                    if (cg == m) e = 0.f;
                    s += e;
                }
                s += __shfl_xor(s, 1, 64);
                s += __shfl_xor(s, 2, 64);
                s += __shfl_xor(s, 4, 64);
                s += __shfl_xor(s, 8, 64);
                if (lx == 0) atomicAdd(&S[m], s);
            }
        }
    } else {
        // off-diagonal: row sums + column sums (transposed half), pos capture
        float colpart[4] = {0.f, 0.f, 0.f, 0.f};
#pragma unroll
        for (int i = 0; i < 4; ++i) {
#pragma unroll
            for (int r = 0; r < 4; ++r) {
                int m = rt * 128 + wrow + i * 16 + quad * 4 + r;
                int partner = m + BS_;          // only m<BS_ can hit in upper triangle
                float s = 0.f;
#pragma unroll
                for (int j = 0; j < 4; ++j) {
                    int cg = colb + j * 16;
                    float logit = acc[i][j][r] * TEMP_INV;
                    float e = __expf(logit);
                    if (cg == partner) { pos[m] = logit; pos[cg] = logit; }
                    s += e;
                    colpart[j] += e;
                }
                s += __shfl_xor(s, 1, 64);
                s += __shfl_xor(s, 2, 64);
                s += __shfl_xor(s, 4, 64);
                s += __shfl_xor(s, 8, 64);
                if (lx == 0) atomicAdd(&S[m], s);
            }
        }
#pragma unroll
        for (int j = 0; j < 4; ++j) {
            float cs = colpart[j];
            cs += __shfl_xor(cs, 16, 64);
            cs += __shfl_xor(cs, 32, 64);
            if (quad == 0) atomicAdd(&S[colb + j * 16], cs);
        }
    }

    // ---- fused loss: last block to finish reduces S/pos --------------------
    __threadfence();                            // release our S/pos writes
    __shared__ uint is_last;
    if (tid == 0) {
        uint old = __hip_atomic_fetch_add(done, 1u, __ATOMIC_ACQ_REL,
                                          __HIP_MEMORY_SCOPE_AGENT);
        is_last = (old == NTILES_ - 1) ? 1u : 0u;
    }
    __syncthreads();
    if (is_last) {
        __threadfence();                        // acquire side
        float a = 0.f;
        for (int i = tid; i < N_; i += 256) {
            float sv = __hip_atomic_load(&S[i], __ATOMIC_RELAXED,
                                         __HIP_MEMORY_SCOPE_AGENT);
            float pv = __hip_atomic_load(&pos[i], __ATOMIC_RELAXED,
                                         __HIP_MEMORY_SCOPE_AGENT);
            a += logf(sv) - pv;
        }
#pragma unroll
        for (int m = 32; m >= 1; m >>= 1) a += __shfl_xor(a, m, 64);
        __shared__ float part[4];
        if (lane == 0) part[wid] = a;
        __syncthreads();
        if (tid == 0)
            out[0] = (part[0] + part[1] + part[2] + part[3]) * (1.0f / N_);
    }
}

extern "C" void kernel_launch(void* const* d_in, const int* in_sizes, int n_in,
                              void* d_out, int out_size, void* d_ws, size_t ws_size,
                              hipStream_t stream) {
    const float* zi = (const float*)d_in[0];
    const float* zj = (const float*)d_in[1];
    float* out = (float*)d_out;

    char* ws = (char*)d_ws;
    unsigned char* zn = (unsigned char*)ws;                    // N_*256 B fp4 = 1.31 MB
    float* S    = (float*)(ws + (size_t)N_ * CB4_);
    float* pos  = S + N_;
    uint*  done = (uint*)(pos + N_);

    pool_norm_kernel<<<N_ / 4, 256, 0, stream>>>(zi, zj, (uint*)zn, S, done);
    simexp_mfma<<<NTILES_, 256, 0, stream>>>(zn, S, pos, done, out);
}

// Round 7
// 113.627 us; speedup vs baseline: 1.4597x; 1.4597x over previous
//
#include <hip/hip_runtime.h>
#include <hip/hip_bf16.h>
#include <math.h>

#define B_       512
#define SEQ_     25
#define C_       512
#define W_       5
#define BS_      2560          // B_*W_ rows per input
#define N_       5120          // 2*BS_
#define NT_      40            // N_/128 tile rows
#define NTILES_  (NT_ * (NT_ + 1) / 2)   // 820 upper-triangle tiles
#define CB4_     256           // bytes per zn row (512 fp4 nibbles)
#define TEMP_INV 10.0f
#define EPS_     1e-8f

typedef __attribute__((ext_vector_type(4))) int   int4v;
typedef __attribute__((ext_vector_type(8))) int   int8v;
typedef __attribute__((ext_vector_type(4))) float floatx4;

#define GAS(p) ((__attribute__((address_space(1))) void*)(void*)(p))
#define LAS(p) ((__attribute__((address_space(3))) void*)(p))

// e2m1 quantize of x (pre-scaled by 32): codes 0..7 = {0,.5,1,1.5,2,3,4,6}
static __device__ __forceinline__ uint fp4q(float x) {
    float m = fabsf(x);
    uint c;
    if      (m < 0.25f) c = 0;
    else if (m < 0.75f) c = 1;
    else if (m < 1.25f) c = 2;
    else if (m < 1.75f) c = 3;
    else if (m < 2.5f)  c = 4;
    else if (m < 3.5f)  c = 5;
    else if (m < 5.0f)  c = 6;
    else                c = 7;
    return c | (x < 0.f ? 8u : 0u);
}

// ---- kernel 1: pool (5-wide bins) + L2 normalize + fp4(e2m1) pack -----------
__global__ __launch_bounds__(256) void pool_norm_kernel(const float* __restrict__ zi,
                                                        const float* __restrict__ zj,
                                                        uint* __restrict__ zn4,
                                                        float* __restrict__ S,
                                                        uint* __restrict__ done) {
    int row = blockIdx.x * 4 + (threadIdx.x >> 6);
    int lane = threadIdx.x & 63;
    const float* src = (row < BS_) ? zi : zj;
    int rr = (row < BS_) ? row : row - BS_;
    int b = rr / W_;
    int w = rr - b * W_;
    const float4* base4 = (const float4*)(src + ((size_t)b * SEQ_ + (size_t)w * W_) * C_);
    float4 v0 = {0, 0, 0, 0}, v1 = {0, 0, 0, 0};
#pragma unroll
    for (int t = 0; t < W_; ++t) {
        float4 a = base4[t * 128 + lane * 2];
        float4 c = base4[t * 128 + lane * 2 + 1];
        v0.x += a.x; v0.y += a.y; v0.z += a.z; v0.w += a.w;
        v1.x += c.x; v1.y += c.y; v1.z += c.z; v1.w += c.w;
    }
    float ss = v0.x * v0.x + v0.y * v0.y + v0.z * v0.z + v0.w * v0.w
             + v1.x * v1.x + v1.y * v1.y + v1.z * v1.z + v1.w * v1.w;
#pragma unroll
    for (int m = 32; m >= 1; m >>= 1) ss += __shfl_xor(ss, m, 64);
    // 1/5 pooling scale folds into 1/norm (cosine is scale-invariant)
    float inv32 = 32.0f / fmaxf(sqrtf(ss), EPS_);
    uint p = fp4q(v0.x * inv32);
    p |= fp4q(v0.y * inv32) << 4;
    p |= fp4q(v0.z * inv32) << 8;
    p |= fp4q(v0.w * inv32) << 12;
    p |= fp4q(v1.x * inv32) << 16;
    p |= fp4q(v1.y * inv32) << 20;
    p |= fp4q(v1.z * inv32) << 24;
    p |= fp4q(v1.w * inv32) << 28;
    zn4[(size_t)row * 64 + lane] = p;
    if (lane == 0) S[row] = 0.f;                    // replaces memset launch
    if (row == 0 && lane == 0) done[0] = 0u;        // last-block counter init
}

// ---- kernel 2: upper-tri 128x128 tiles, MX-fp4, BK=128B (2 iters), fused loss
// R4-proven barriered K-loop. Loss fusion uses ONLY cache-bypassing device-
// scope atomics (no agent fences -> no buffer_wbl2/inv L2 flushes, the R5 bug):
// S via atomicAdd, pos via relaxed agent atomic stores, counter via relaxed
// fetch_add AFTER __syncthreads (barrier drains each wave's vmcnt first).
__global__ __launch_bounds__(256) void simexp_mfma(const unsigned char* __restrict__ zn,
                                                   float* __restrict__ S,
                                                   float* __restrict__ pos,
                                                   uint* __restrict__ done,
                                                   float* __restrict__ out) {
    __shared__ __align__(16) unsigned char As[128 * 128];   // 16 KB
    __shared__ __align__(16) unsigned char Bs[128 * 128];   // 16 KB
    // decode upper-triangle tile index (scalar, uniform)
    int t = blockIdx.x, rt = 0, rem = NT_;
    while (t >= rem) { t -= rem; rem--; rt++; }
    int ct = rt + t;

    int tid = threadIdx.x;
    int wid = tid >> 6, lane = tid & 63;
    int lrow = lane >> 3, lk = lane & 7;        // staging: 8 rows x 8 chunks of 16B
    int lx = lane & 15, quad = lane >> 4;       // mfma fragment indexing
    int wrow = (wid >> 1) * 64, wcol = (wid & 1) * 64;
    int swz = (lk ^ lrow) * 16;                 // global-side chunk swizzle

    union frag { int8v v8; int4v v4[2]; };
    floatx4 acc[4][4] = {};

    for (int k0 = 0; k0 < CB4_; k0 += 128) {    // 2 iters, 256 K-elems each
#pragma unroll
        for (int c = 0; c < 4; ++c) {
            int r = wid * 32 + c * 8 + lrow;    // r&7 == lrow
            __builtin_amdgcn_global_load_lds(
                GAS(zn + (size_t)(rt * 128 + r) * CB4_ + k0 + swz),
                LAS(As + (wid * 32 + c * 8) * 128), 16, 0, 0);
            __builtin_amdgcn_global_load_lds(
                GAS(zn + (size_t)(ct * 128 + r) * CB4_ + k0 + swz),
                LAS(Bs + (wid * 32 + c * 8) * 128), 16, 0, 0);
        }
        __syncthreads();
#pragma unroll
        for (int ks = 0; ks < 2; ++ks) {        // two K=128 MFMA slices per iter
            frag af[4], bf[4];
#pragma unroll
            for (int tt = 0; tt < 4; ++tt) {
                int m = wrow + tt * 16 + lx;
                af[tt].v4[0] = *(const int4v*)&As[m * 128 + (((ks * 4 + quad) ^ (m & 7)) * 16)];
                af[tt].v4[1] = (int4v)(0);
                int n = wcol + tt * 16 + lx;
                bf[tt].v4[0] = *(const int4v*)&Bs[n * 128 + (((ks * 4 + quad) ^ (n & 7)) * 16)];
                bf[tt].v4[1] = (int4v)(0);
            }
#pragma unroll
            for (int i = 0; i < 4; ++i)
#pragma unroll
                for (int j = 0; j < 4; ++j)
                    acc[i][j] = __builtin_amdgcn_mfma_scale_f32_16x16x128_f8f6f4(
                        af[i].v8, bf[j].v8, acc[i][j],
                        4, 4,                    // cbsz=fp4(e2m1), blgp=fp4(e2m1)
                        0, 0x7A7A7A7A,           // scale A: E8M0 2^-5
                        0, 0x7A7A7A7A);          // scale B: E8M0 2^-5
        }
        __syncthreads();
    }

    // epilogue: D layout col=lane&15, row=quad*4+reg (shape-determined)
    int colb = ct * 128 + wcol + lx;
    if (rt == ct) {
        // diagonal tile: mask diagonal, row sums only (pos never here)
#pragma unroll
        for (int i = 0; i < 4; ++i) {
#pragma unroll
            for (int r = 0; r < 4; ++r) {
                int m = rt * 128 + wrow + i * 16 + quad * 4 + r;
                float s = 0.f;
#pragma unroll
                for (int j = 0; j < 4; ++j) {
                    int cg = colb + j * 16;
                    float e = __expf(acc[i][j][r] * TEMP_INV);
                    if (cg == m) e = 0.f;
                    s += e;
                }
                s += __shfl_xor(s, 1, 64);
                s += __shfl_xor(s, 2, 64);
                s += __shfl_xor(s, 4, 64);
                s += __shfl_xor(s, 8, 64);
                if (lx == 0) atomicAdd(&S[m], s);
            }
        }
    } else {
        // off-diagonal: row sums + column sums (transposed half), pos capture
        float colpart[4] = {0.f, 0.f, 0.f, 0.f};
#pragma unroll
        for (int i = 0; i < 4; ++i) {
#pragma unroll
            for (int r = 0; r < 4; ++r) {
                int m = rt * 128 + wrow + i * 16 + quad * 4 + r;
                int partner = m + BS_;          // only m<BS_ can hit in upper triangle
                float s = 0.f;
#pragma unroll
                for (int j = 0; j < 4; ++j) {
                    int cg = colb + j * 16;
                    float logit = acc[i][j][r] * TEMP_INV;
                    float e = __expf(logit);
                    if (cg == partner) {        // unique writer for both entries
                        __hip_atomic_store(&pos[m], logit, __ATOMIC_RELAXED,
                                           __HIP_MEMORY_SCOPE_AGENT);
                        __hip_atomic_store(&pos[cg], logit, __ATOMIC_RELAXED,
                                           __HIP_MEMORY_SCOPE_AGENT);
                    }
                    s += e;
                    colpart[j] += e;
                }
                s += __shfl_xor(s, 1, 64);
                s += __shfl_xor(s, 2, 64);
                s += __shfl_xor(s, 4, 64);
                s += __shfl_xor(s, 8, 64);
                if (lx == 0) atomicAdd(&S[m], s);
            }
        }
#pragma unroll
        for (int j = 0; j < 4; ++j) {
            float cs = colpart[j];
            cs += __shfl_xor(cs, 16, 64);
            cs += __shfl_xor(cs, 32, 64);
            if (quad == 0) atomicAdd(&S[colb + j * 16], cs);
        }
    }

    // ---- fused loss: last block reduces S/pos (atomics only, no fences) ----
    asm volatile("s_waitcnt vmcnt(0)" ::: "memory");  // belt+braces: own atomics done
    __syncthreads();                 // all 4 waves drained before the increment
    __shared__ uint is_last;
    if (tid == 0) {
        uint old = __hip_atomic_fetch_add(done, 1u, __ATOMIC_RELAXED,
                                          __HIP_MEMORY_SCOPE_AGENT);
        is_last = (old == NTILES_ - 1) ? 1u : 0u;
    }
    __syncthreads();
    if (is_last) {
        float a = 0.f;
        for (int i = tid; i < N_; i += 256) {
            float sv = __hip_atomic_load(&S[i], __ATOMIC_RELAXED,
                                         __HIP_MEMORY_SCOPE_AGENT);
            float pv = __hip_atomic_load(&pos[i], __ATOMIC_RELAXED,
                                         __HIP_MEMORY_SCOPE_AGENT);
            a += logf(sv) - pv;
        }
#pragma unroll
        for (int m = 32; m >= 1; m >>= 1) a += __shfl_xor(a, m, 64);
        __shared__ float part[4];
        if (lane == 0) part[wid] = a;
        __syncthreads();
        if (tid == 0)
            out[0] = (part[0] + part[1] + part[2] + part[3]) * (1.0f / N_);
    }
}

extern "C" void kernel_launch(void* const* d_in, const int* in_sizes, int n_in,
                              void* d_out, int out_size, void* d_ws, size_t ws_size,
                              hipStream_t stream) {
    const float* zi = (const float*)d_in[0];
    const float* zj = (const float*)d_in[1];
    float* out = (float*)d_out;

    char* ws = (char*)d_ws;
    unsigned char* zn = (unsigned char*)ws;                    // N_*256 B fp4 = 1.31 MB
    float* S    = (float*)(ws + (size_t)N_ * CB4_);
    float* pos  = S + N_;
    uint*  done = (uint*)(pos + N_);

    pool_norm_kernel<<<N_ / 4, 256, 0, stream>>>(zi, zj, (uint*)zn, S, done);
    simexp_mfma<<<NTILES_, 256, 0, stream>>>(zn, S, pos, done, out);
}

// Round 8
// 106.428 us; speedup vs baseline: 1.5585x; 1.0676x over previous
//
#include <hip/hip_runtime.h>
#include <hip/hip_bf16.h>
#include <math.h>

#define B_       512
#define SEQ_     25
#define C_       512
#define W_       5
#define BS_      2560          // B_*W_ rows per input
#define N_       5120          // 2*BS_
#define NT_      40            // N_/128 tile rows
#define NTILES_  (NT_ * (NT_ + 1) / 2)   // 820 upper-triangle tiles
#define CB4_     256           // bytes per zn row (512 fp4 nibbles)
#define TEMP_INV 10.0f
#define EPS_     1e-8f

typedef __attribute__((ext_vector_type(4))) int   int4v;
typedef __attribute__((ext_vector_type(8))) int   int8v;
typedef __attribute__((ext_vector_type(4))) float floatx4;

#define GAS(p) ((__attribute__((address_space(1))) void*)(void*)(p))
#define LAS(p) ((__attribute__((address_space(3))) void*)(p))

// e2m1 quantize of x (pre-scaled by 32): codes 0..7 = {0,.5,1,1.5,2,3,4,6}
static __device__ __forceinline__ uint fp4q(float x) {
    float m = fabsf(x);
    uint c;
    if      (m < 0.25f) c = 0;
    else if (m < 0.75f) c = 1;
    else if (m < 1.25f) c = 2;
    else if (m < 1.75f) c = 3;
    else if (m < 2.5f)  c = 4;
    else if (m < 3.5f)  c = 5;
    else if (m < 5.0f)  c = 6;
    else                c = 7;
    return c | (x < 0.f ? 8u : 0u);
}

// ---- kernel 1: pool (5-wide bins) + L2 normalize + fp4(e2m1) pack -----------
__global__ __launch_bounds__(256) void pool_norm_kernel(const float* __restrict__ zi,
                                                        const float* __restrict__ zj,
                                                        uint* __restrict__ zn4,
                                                        float* __restrict__ S,
                                                        float* __restrict__ out) {
    int row = blockIdx.x * 4 + (threadIdx.x >> 6);
    int lane = threadIdx.x & 63;
    const float* src = (row < BS_) ? zi : zj;
    int rr = (row < BS_) ? row : row - BS_;
    int b = rr / W_;
    int w = rr - b * W_;
    const float4* base4 = (const float4*)(src + ((size_t)b * SEQ_ + (size_t)w * W_) * C_);
    float4 v0 = {0, 0, 0, 0}, v1 = {0, 0, 0, 0};
#pragma unroll
    for (int t = 0; t < W_; ++t) {
        float4 a = base4[t * 128 + lane * 2];
        float4 c = base4[t * 128 + lane * 2 + 1];
        v0.x += a.x; v0.y += a.y; v0.z += a.z; v0.w += a.w;
        v1.x += c.x; v1.y += c.y; v1.z += c.z; v1.w += c.w;
    }
    float ss = v0.x * v0.x + v0.y * v0.y + v0.z * v0.z + v0.w * v0.w
             + v1.x * v1.x + v1.y * v1.y + v1.z * v1.z + v1.w * v1.w;
#pragma unroll
    for (int m = 32; m >= 1; m >>= 1) ss += __shfl_xor(ss, m, 64);
    // 1/5 pooling scale folds into 1/norm (cosine is scale-invariant)
    float inv32 = 32.0f / fmaxf(sqrtf(ss), EPS_);
    uint p = fp4q(v0.x * inv32);
    p |= fp4q(v0.y * inv32) << 4;
    p |= fp4q(v0.z * inv32) << 8;
    p |= fp4q(v0.w * inv32) << 12;
    p |= fp4q(v1.x * inv32) << 16;
    p |= fp4q(v1.y * inv32) << 20;
    p |= fp4q(v1.z * inv32) << 24;
    p |= fp4q(v1.w * inv32) << 28;
    zn4[(size_t)row * 64 + lane] = p;
    if (lane == 0) S[row] = 0.f;                    // replaces memset launch
    if (row == 0 && lane == 0) out[0] = 0.f;        // loss accumulator init
}

// ---- kernel 2: upper-tri 128x128 tiles, MX-fp4, double-buffered staging -----
// R4 structure (4 K-iters of 64B/row) + ping-pong LDS: iter k+1's
// global_load_lds issue right after the barrier, ahead of iter k's MFMAs, so
// L2 latency hides behind compute instead of serializing at each drain.
__global__ __launch_bounds__(256) void simexp_mfma(const unsigned char* __restrict__ zn,
                                                   float* __restrict__ S,
                                                   float* __restrict__ pos) {
    __shared__ __align__(16) unsigned char As[2][128 * 64];   // 2 x 8 KB
    __shared__ __align__(16) unsigned char Bs[2][128 * 64];   // 2 x 8 KB
    // decode upper-triangle tile index (scalar, uniform)
    int t = blockIdx.x, rt = 0, rem = NT_;
    while (t >= rem) { t -= rem; rem--; rt++; }
    int ct = rt + t;

    int tid = threadIdx.x;
    int wid = tid >> 6, lane = tid & 63;
    int lrow = lane >> 2, lk = lane & 3;        // staging: 16 rows x 4 chunks of 16B
    int lx = lane & 15, quad = lane >> 4;       // mfma fragment indexing
    int wrow = (wid >> 1) * 64, wcol = (wid & 1) * 64;

    const unsigned char* gA[2]; const unsigned char* gB[2];
    int loff[2];
#pragma unroll
    for (int c = 0; c < 2; ++c) {
        int r = wid * 32 + c * 16 + lrow;
        gA[c] = zn + (size_t)(rt * 128 + r) * CB4_ + ((lk ^ (lrow & 3)) * 16);
        gB[c] = zn + (size_t)(ct * 128 + r) * CB4_ + ((lk ^ (lrow & 3)) * 16);
        loff[c] = (wid * 32 + c * 16) * 64;     // HW appends lane*16B
    }

    union frag { int8v v8; int4v v4[2]; };
    floatx4 acc[4][4] = {};

    // prologue: stage iter 0 into buffer 0
#pragma unroll
    for (int c = 0; c < 2; ++c) {
        __builtin_amdgcn_global_load_lds(GAS(gA[c]), LAS(As[0] + loff[c]), 16, 0, 0);
        __builtin_amdgcn_global_load_lds(GAS(gB[c]), LAS(Bs[0] + loff[c]), 16, 0, 0);
    }

    for (int k = 0; k < 4; ++k) {               // 4 iters, 128 K-elems each
        int cur = k & 1, nxt = cur ^ 1;
        __syncthreads();                        // buf[cur] ready (vmcnt drained)
        if (k < 3) {                            // prefetch iter k+1 into buf[nxt]
            int k0 = (k + 1) * 64;
#pragma unroll
            for (int c = 0; c < 2; ++c) {
                __builtin_amdgcn_global_load_lds(GAS(gA[c] + k0), LAS(As[nxt] + loff[c]), 16, 0, 0);
                __builtin_amdgcn_global_load_lds(GAS(gB[c] + k0), LAS(Bs[nxt] + loff[c]), 16, 0, 0);
            }
        }
        frag af[4], bf[4];
#pragma unroll
        for (int tt = 0; tt < 4; ++tt) {
            int m = wrow + tt * 16 + lx;
            af[tt].v4[0] = *(const int4v*)&As[cur][m * 64 + ((quad ^ (m & 3)) * 16)];
            af[tt].v4[1] = (int4v)(0);
            int n = wcol + tt * 16 + lx;
            bf[tt].v4[0] = *(const int4v*)&Bs[cur][n * 64 + ((quad ^ (n & 3)) * 16)];
            bf[tt].v4[1] = (int4v)(0);
        }
#pragma unroll
        for (int i = 0; i < 4; ++i)
#pragma unroll
            for (int j = 0; j < 4; ++j)
                acc[i][j] = __builtin_amdgcn_mfma_scale_f32_16x16x128_f8f6f4(
                    af[i].v8, bf[j].v8, acc[i][j],
                    4, 4,                    // cbsz=fp4(e2m1), blgp=fp4(e2m1)
                    0, 0x7A7A7A7A,           // scale A: E8M0 2^-5
                    0, 0x7A7A7A7A);          // scale B: E8M0 2^-5
    }

    // epilogue: D layout col=lane&15, row=quad*4+reg (shape-determined)
    int colb = ct * 128 + wcol + lx;
    if (rt == ct) {
        // diagonal tile: mask diagonal, row sums only (pos never here)
#pragma unroll
        for (int i = 0; i < 4; ++i) {
#pragma unroll
            for (int r = 0; r < 4; ++r) {
                int m = rt * 128 + wrow + i * 16 + quad * 4 + r;
                float s = 0.f;
#pragma unroll
                for (int j = 0; j < 4; ++j) {
                    int cg = colb + j * 16;
                    float e = __expf(acc[i][j][r] * TEMP_INV);
                    if (cg == m) e = 0.f;
                    s += e;
                }
                s += __shfl_xor(s, 1, 64);
                s += __shfl_xor(s, 2, 64);
                s += __shfl_xor(s, 4, 64);
                s += __shfl_xor(s, 8, 64);
                if (lx == 0) atomicAdd(&S[m], s);
            }
        }
    } else {
        // off-diagonal: row sums + column sums (transposed half), pos capture
        float colpart[4] = {0.f, 0.f, 0.f, 0.f};
#pragma unroll
        for (int i = 0; i < 4; ++i) {
#pragma unroll
            for (int r = 0; r < 4; ++r) {
                int m = rt * 128 + wrow + i * 16 + quad * 4 + r;
                int partner = m + BS_;          // only m<BS_ can hit in upper triangle
                float s = 0.f;
#pragma unroll
                for (int j = 0; j < 4; ++j) {
                    int cg = colb + j * 16;
                    float logit = acc[i][j][r] * TEMP_INV;
                    float e = __expf(logit);
                    if (cg == partner) { pos[m] = logit; pos[cg] = logit; }
                    s += e;
                    colpart[j] += e;
                }
                s += __shfl_xor(s, 1, 64);
                s += __shfl_xor(s, 2, 64);
                s += __shfl_xor(s, 4, 64);
                s += __shfl_xor(s, 8, 64);
                if (lx == 0) atomicAdd(&S[m], s);
            }
        }
#pragma unroll
        for (int j = 0; j < 4; ++j) {
            float cs = colpart[j];
            cs += __shfl_xor(cs, 16, 64);
            cs += __shfl_xor(cs, 32, 64);
            if (quad == 0) atomicAdd(&S[colb + j * 16], cs);
        }
    }
}

// ---- kernel 3: loss = sum(log(S) - pos) / N  (20 blocks, atomic accumulate) -
__global__ __launch_bounds__(256) void loss_kernel(const float* __restrict__ S,
                                                   const float* __restrict__ pos,
                                                   float* __restrict__ out) {
    int i = blockIdx.x * 256 + threadIdx.x;
    float a = logf(S[i]) - pos[i];
#pragma unroll
    for (int m = 32; m >= 1; m >>= 1) a += __shfl_xor(a, m, 64);
    __shared__ float part[4];
    int lane = threadIdx.x & 63, wid = threadIdx.x >> 6;
    if (lane == 0) part[wid] = a;
    __syncthreads();
    if (threadIdx.x == 0)
        atomicAdd(out, (part[0] + part[1] + part[2] + part[3]) * (1.0f / N_));
}

extern "C" void kernel_launch(void* const* d_in, const int* in_sizes, int n_in,
                              void* d_out, int out_size, void* d_ws, size_t ws_size,
                              hipStream_t stream) {
    const float* zi = (const float*)d_in[0];
    const float* zj = (const float*)d_in[1];
    float* out = (float*)d_out;

    char* ws = (char*)d_ws;
    unsigned char* zn = (unsigned char*)ws;                    // N_*256 B fp4 = 1.31 MB
    float* S   = (float*)(ws + (size_t)N_ * CB4_);
    float* pos = S + N_;

    pool_norm_kernel<<<N_ / 4, 256, 0, stream>>>(zi, zj, (uint*)zn, S, out);
    simexp_mfma<<<NTILES_, 256, 0, stream>>>(zn, S, pos);
    loss_kernel<<<N_ / 256, 256, 0, stream>>>(S, pos, out);
}